// Round 8
// baseline (395.852 us; speedup 1.0000x reference)
//
#include <hip/hip_runtime.h>

// Problem constants
constexpr int Bb = 16;      // batch
constexpr int Nn = 256;     // regions
constexpr int Hh = 768;     // hidden
constexpr int Pp = 2048;    // proj dim
constexpr int Rr = 3;       // relation types
constexpr int Mm = Bb * Nn; // 4096 flattened rows
constexpr int HA = 896;     // augmented hidden (768 + 1 bias row + pad)
constexpr int KA = 2080;    // augmented K for Bop GEMM (2048 + 32)
constexpr int JA = Rr * HA; // 2688

typedef __bf16 bf16_t;
typedef __bf16 bf16x8 __attribute__((ext_vector_type(8)));
typedef __bf16 bf16x4 __attribute__((ext_vector_type(4)));
typedef float  floatx4 __attribute__((ext_vector_type(4)));

// async global->LDS, 16B per lane; LDS dest = wave-uniform base + lane*16
__device__ __forceinline__ void gld_lds16(const void* g, void* l) {
    __builtin_amdgcn_global_load_lds(
        (__attribute__((address_space(1))) void*)g,
        (__attribute__((address_space(3))) void*)l,
        16, 0, 0);
}

// ---------------------------------------------------------------------------
// F_aug [4096, 896] bf16: cols 0..767 = F, col 768 = 1, cols 769..895 = 0
// ---------------------------------------------------------------------------
__global__ __launch_bounds__(256) void build_Faug(
    const float* __restrict__ F, bf16_t* __restrict__ out)
{
    const int idx = blockIdx.x * 256 + threadIdx.x;   // over 4096 * (896/4)
    const int n = idx / (HA / 4), c4 = idx % (HA / 4);
    const int h = c4 * 4;
    bf16x4 o;
    if (h < Hh) {
        float4 v = *(const float4*)(F + (size_t)n * Hh + h);
        o = { (bf16_t)v.x, (bf16_t)v.y, (bf16_t)v.z, (bf16_t)v.w };
    } else {
        #pragma unroll
        for (int e = 0; e < 4; ++e) o[e] = (bf16_t)((h + e == Hh) ? 1.0f : 0.0f);
    }
    *(bf16x4*)(out + (size_t)n * HA + h) = o;
}

// ---------------------------------------------------------------------------
// tWaug [896, 2048]: rows j<768 = tW^T (tW[q,j]), row 768 = bt[q], rows>768 = 0
// ---------------------------------------------------------------------------
__global__ __launch_bounds__(256) void build_tWaug(
    const float* __restrict__ tW, const float* __restrict__ bt,
    bf16_t* __restrict__ out)
{
    __shared__ float t[32][33];
    const int j0 = blockIdx.y * 32, q0 = blockIdx.x * 32;
    const int tx = threadIdx.x, ty = threadIdx.y;
    #pragma unroll
    for (int s = 0; s < 4; ++s) {
        const int q = q0 + ty + s * 8, j = j0 + tx;
        t[ty + s * 8][tx] = (j < Hh) ? tW[(size_t)q * Hh + j] : 0.0f;
    }
    __syncthreads();
    #pragma unroll
    for (int s = 0; s < 4; ++s) {
        const int j = j0 + ty + s * 8, q = q0 + tx;
        float v = t[tx][ty + s * 8];
        if (j == Hh) v = bt[q];
        else if (j > Hh) v = 0.0f;
        out[(size_t)j * Pp + q] = (bf16_t)v;
    }
}

// ---------------------------------------------------------------------------
// hWaug [896, 2080]: rows h<768 = hW^T, row 768 = [bh | 1 @ p=2048], rows>768=0
// ---------------------------------------------------------------------------
__global__ __launch_bounds__(256) void build_hWaug(
    const float* __restrict__ hW, const float* __restrict__ bh,
    bf16_t* __restrict__ out)
{
    __shared__ float t[32][33];
    const int h0 = blockIdx.y * 32, p0 = blockIdx.x * 32;
    const int tx = threadIdx.x, ty = threadIdx.y;
    #pragma unroll
    for (int s = 0; s < 4; ++s) {
        const int p = p0 + ty + s * 8, h = h0 + tx;
        t[ty + s * 8][tx] = (p < Pp && h < Hh) ? hW[(size_t)p * Hh + h] : 0.0f;
    }
    __syncthreads();
    #pragma unroll
    for (int s = 0; s < 4; ++s) {
        const int h = h0 + ty + s * 8, p = p0 + tx;
        float v = t[tx][ty + s * 8];
        if (h == Hh) v = (p < Pp) ? bh[p] : (p == Pp ? 1.0f : 0.0f);
        else if (h > Hh) v = 0.0f;
        out[(size_t)h * KA + p] = (bf16_t)v;
    }
}

// ---------------------------------------------------------------------------
// fill T1taug col stripe [j][2048..2079]: col 2048 = (j==768 ? bil_b[r] : 0)
// ---------------------------------------------------------------------------
__global__ __launch_bounds__(256) void fill_T1cols(
    const float* __restrict__ bil_b, bf16_t* __restrict__ T1)
{
    const int idx = blockIdx.x * 256 + threadIdx.x;
    if (idx >= Rr * HA) return;
    const int r = idx / HA, j = idx % HA;
    bf16_t* p = T1 + (size_t)r * HA * KA + (size_t)j * KA + Pp;
    p[0] = (bf16_t)(j == Hh ? bil_b[r] : 0.0f);
    #pragma unroll
    for (int e = 1; e < 32; ++e) p[e] = (bf16_t)0.0f;
}

// ---------------------------------------------------------------------------
// T1 = tWaug @ bil_W[r]^T  — LDS-FREE wave-level NT GEMM, A bf16 / B fp32.
// Each wave owns a 64x64 tile; fragments loaded straight from global into
// registers (lane reads its 16B MFMA fragment). No LDS, no __syncthreads:
// the compiler software-pipelines with fine-grained s_waitcnt vmcnt(N).
// 2-stage, distance-2 explicit prefetch. Block = 4 waves (2x2) = 128x128.
// grid (Pp/128, HA/128, Rr)
// ---------------------------------------------------------------------------
__global__ __launch_bounds__(256) void t1_wave_kernel(
    const bf16_t* __restrict__ A,   // tWaug [HA, Pp]
    const float*  __restrict__ B,   // bil_W [Rr][Pp][Pp]
    bf16_t* __restrict__ C)         // T1taug [Rr][HA][KA]
{
    B += (size_t)blockIdx.z * Pp * Pp;
    C += (size_t)blockIdx.z * HA * KA;

    const int tid = threadIdx.x;
    const int w = tid >> 6;
    const int l = tid & 63;
    const int m0 = blockIdx.y * 128 + ((w >> 1) << 6);
    const int n0 = blockIdx.x * 128 + ((w & 1) << 6);
    const int fr = l & 15;
    const int fq = (l >> 4) << 3;

    const bf16_t* pa = A + (size_t)(m0 + fr) * Pp + fq;
    const float*  pb = B + (size_t)(n0 + fr) * Pp + fq;

    bf16x8  sa[2][4];
    floatx4 sb[2][8];
    floatx4 acc[4][4] = {};

    auto load = [&](int s, int k0) {
        #pragma unroll
        for (int i = 0; i < 4; ++i)
            sa[s][i] = *(const bf16x8*)(pa + (size_t)(i * 16) * Pp + k0);
        #pragma unroll
        for (int j = 0; j < 4; ++j) {
            const float* q = pb + (size_t)(j * 16) * Pp + k0;
            sb[s][j * 2]     = *(const floatx4*)q;
            sb[s][j * 2 + 1] = *(const floatx4*)(q + 4);
        }
    };
    auto compute = [&](int s) {
        bf16x8 bb[4];
        #pragma unroll
        for (int j = 0; j < 4; ++j)
            #pragma unroll
            for (int e = 0; e < 4; ++e) {
                bb[j][e]     = (bf16_t)sb[s][j * 2][e];
                bb[j][e + 4] = (bf16_t)sb[s][j * 2 + 1][e];
            }
        #pragma unroll
        for (int i = 0; i < 4; ++i)
            #pragma unroll
            for (int j = 0; j < 4; ++j)
                acc[i][j] = __builtin_amdgcn_mfma_f32_16x16x32_bf16(sa[s][i], bb[j], acc[i][j], 0, 0, 0);
    };

    constexpr int steps = Pp / 32;  // 64 (even)
    load(0, 0);
    load(1, 32);
    for (int k = 0; k < steps; k += 2) {
        compute(0);
        if (k + 2 < steps) load(0, (k + 2) * 32);
        compute(1);
        if (k + 3 < steps) load(1, (k + 3) * 32);
    }

    const int em = m0 + ((l >> 4) << 2);
    const int en = n0 + (l & 15);
    #pragma unroll
    for (int i = 0; i < 4; ++i)
        #pragma unroll
        for (int j = 0; j < 4; ++j)
            #pragma unroll
            for (int rg = 0; rg < 4; ++rg)
                C[(size_t)(em + i * 16 + rg) * KA + en + j * 16] = (bf16_t)acc[i][j][rg];
}

// ---------------------------------------------------------------------------
// Bop[r] = T1taug[r] @ hWaug^T — LDS-FREE wave-level NT GEMM, bf16 x bf16.
// Wave tile 32(M)x64(N); block = 4 waves (2x2) = 64x128.
// grid (HA/128, HA/64, Rr). K = KA = 2080 (65 steps, odd).
// ---------------------------------------------------------------------------
__global__ __launch_bounds__(256) void bop_wave_kernel(
    const bf16_t* __restrict__ A,   // T1taug [Rr][HA][KA]
    const bf16_t* __restrict__ Bm,  // hWaug [HA][KA]
    bf16_t* __restrict__ C)         // Bop [Rr][HA][HA]
{
    A += (size_t)blockIdx.z * HA * KA;
    C += (size_t)blockIdx.z * HA * HA;

    const int tid = threadIdx.x;
    const int w = tid >> 6;
    const int l = tid & 63;
    const int m0 = blockIdx.y * 64 + ((w >> 1) << 5);
    const int n0 = blockIdx.x * 128 + ((w & 1) << 6);
    const int fr = l & 15;
    const int fq = (l >> 4) << 3;

    const bf16_t* pa = A  + (size_t)(m0 + fr) * KA + fq;
    const bf16_t* pb = Bm + (size_t)(n0 + fr) * KA + fq;

    bf16x8 sa[2][2];
    bf16x8 sb[2][4];
    floatx4 acc[2][4] = {};

    auto load = [&](int s, int k0) {
        #pragma unroll
        for (int i = 0; i < 2; ++i)
            sa[s][i] = *(const bf16x8*)(pa + (size_t)(i * 16) * KA + k0);
        #pragma unroll
        for (int j = 0; j < 4; ++j)
            sb[s][j] = *(const bf16x8*)(pb + (size_t)(j * 16) * KA + k0);
    };
    auto compute = [&](int s) {
        #pragma unroll
        for (int i = 0; i < 2; ++i)
            #pragma unroll
            for (int j = 0; j < 4; ++j)
                acc[i][j] = __builtin_amdgcn_mfma_f32_16x16x32_bf16(sa[s][i], sb[s][j], acc[i][j], 0, 0, 0);
    };

    constexpr int steps = KA / 32;  // 65 (odd)
    load(0, 0);
    load(1, 32);
    for (int k = 0; k < steps - 1; k += 2) {
        compute(0);
        if (k + 2 < steps) load(0, (k + 2) * 32);
        compute(1);
        if (k + 3 < steps) load(1, (k + 3) * 32);
    }
    compute(0);   // final odd step (stage 0 holds k = steps-1)

    const int em = m0 + ((l >> 4) << 2);
    const int en = n0 + (l & 15);
    #pragma unroll
    for (int i = 0; i < 2; ++i)
        #pragma unroll
        for (int j = 0; j < 4; ++j)
            #pragma unroll
            for (int rg = 0; rg < 4; ++rg)
                C[(size_t)(em + i * 16 + rg) * HA + en + j * 16] = (bf16_t)acc[i][j][rg];
}

// ---------------------------------------------------------------------------
// 128x128-tile bf16 NT GEMM, double-buffered LDS (for FG)
// ---------------------------------------------------------------------------
__global__ __launch_bounds__(256) void gemm_nt_128(
    const bf16_t* __restrict__ A, int lda,
    const bf16_t* __restrict__ B, int ldb,
    bf16_t* __restrict__ C, int ldc, int K)
{
    __shared__ bf16_t As[2][128 * 32];
    __shared__ bf16_t Bs[2][128 * 32];

    const int tid = threadIdx.x;
    const int w = tid >> 6;
    const int l = tid & 63;
    const int m0 = blockIdx.y * 128;
    const int n0 = blockIdx.x * 128;

    const int srow = (w << 4) + (l >> 2);
    const int scol = (l & 3) << 3;
    const bf16_t* ga0 = A + (size_t)(m0 + srow) * lda + scol;
    const bf16_t* ga1 = ga0 + (size_t)64 * lda;
    const bf16_t* gb0 = B + (size_t)(n0 + srow) * ldb + scol;
    const bf16_t* gb1 = gb0 + (size_t)64 * ldb;

    const int wm = (w >> 1) << 6;
    const int wn = (w & 1) << 6;
    const int fr = l & 15;
    const int fq = (l >> 4) << 3;

    floatx4 acc[4][4] = {};

    {
        char* a = (char*)As[0] + (w << 10);
        char* b = (char*)Bs[0] + (w << 10);
        gld_lds16(ga0, a); gld_lds16(ga1, a + 4096);
        gld_lds16(gb0, b); gld_lds16(gb1, b + 4096);
        ga0 += 32; ga1 += 32; gb0 += 32; gb1 += 32;
    }

    const int steps = K >> 5;
    for (int k = 0; k < steps; ++k) {
        __syncthreads();
        const int cur = k & 1;
        if (k + 1 < steps) {
            char* a = (char*)As[cur ^ 1] + (w << 10);
            char* b = (char*)Bs[cur ^ 1] + (w << 10);
            gld_lds16(ga0, a); gld_lds16(ga1, a + 4096);
            gld_lds16(gb0, b); gld_lds16(gb1, b + 4096);
            ga0 += 32; ga1 += 32; gb0 += 32; gb1 += 32;
        }

        bf16x8 a[4], b[4];
        #pragma unroll
        for (int i = 0; i < 4; ++i) {
            a[i] = *(const bf16x8*)&As[cur][(wm + i * 16 + fr) * 32 + fq];
            b[i] = *(const bf16x8*)&Bs[cur][(wn + i * 16 + fr) * 32 + fq];
        }
        #pragma unroll
        for (int i = 0; i < 4; ++i)
            #pragma unroll
            for (int j = 0; j < 4; ++j)
                acc[i][j] = __builtin_amdgcn_mfma_f32_16x16x32_bf16(a[i], b[j], acc[i][j], 0, 0, 0);
    }

    const int em = m0 + wm + ((l >> 4) << 2);
    const int en = n0 + wn + (l & 15);
    #pragma unroll
    for (int j = 0; j < 4; ++j) {
        const int n = en + j * 16;
        #pragma unroll
        for (int i = 0; i < 4; ++i) {
            #pragma unroll
            for (int rg = 0; rg < 4; ++rg)
                C[(size_t)(em + i * 16 + rg) * ldc + n] = (bf16_t)(acc[i][j][rg]);
        }
    }
}

// ---------------------------------------------------------------------------
// fused output GEMM, all 3 r per block, dbuf LDS, K=896, 512 threads (8 waves
// -> 2 waves/SIMD at 1 block/CU; wave = 32n x 16m, 6 MFMA/step):
//   logits[b,n,m,r] = sum_h FG[b*Nn+n, r*HA+h] * Faug[b*Nn+m, h]
// grid (Nn/64, Nn/64, Bb) = 256 blocks.
// ---------------------------------------------------------------------------
__global__ __launch_bounds__(512) void gemm_out_fused(
    const bf16_t* __restrict__ FG,    // [Mm, JA]
    const bf16_t* __restrict__ FA,    // [Mm, HA]
    float* __restrict__ OUT)
{
    __shared__ bf16_t S[2][4][64 * 32];  // tiles 0..2 = FG r, 3 = Faug (32KB)

    const int b = blockIdx.z;
    const int n0 = blockIdx.y * 64;
    const int m0 = blockIdx.x * 64;

    const int tid = threadIdx.x;
    const int w = tid >> 6;      // 0..7
    const int l = tid & 63;

    const int srow = ((w & 3) << 4) + (l >> 2);
    const int scol = (l & 3) << 3;
    const int t0 = w >> 2;               // issue0 tile: FG r = 0/1
    const bf16_t* g0 = FG + (size_t)(b * Nn + n0 + srow) * JA + t0 * HA + scol;
    const bf16_t* g1 = (t0 == 0)
        ? FG + (size_t)(b * Nn + n0 + srow) * JA + 2 * HA + scol   // tile2: FG r=2
        : FA + (size_t)(b * Nn + m0 + srow) * HA + scol;           // tile3: Faug

    const int n_off = (w >> 2) << 5;     // 0/32
    const int m_off = (w & 3) << 4;      // 0/16/32/48
    const int fr = l & 15;
    const int fq = (l >> 4) << 3;

    floatx4 acc[Rr][2] = {};

    {
        char* base = (char*)&S[0][0][0];
        gld_lds16(g0, base + (w << 10));        g0 += 32;
        gld_lds16(g1, base + 8192 + (w << 10)); g1 += 32;
    }

    constexpr int STEPS = HA / 32; // 28
    for (int k = 0; k < STEPS; ++k) {
        __syncthreads();
        const int cur = k & 1;
        if (k + 1 < STEPS) {
            char* base = (char*)&S[cur ^ 1][0][0];
            gld_lds16(g0, base + (w << 10));        g0 += 32;
            gld_lds16(g1, base + 8192 + (w << 10)); g1 += 32;
        }

        bf16x8 t = *(const bf16x8*)&S[cur][3][(m_off + fr) * 32 + fq];
        #pragma unroll
        for (int r = 0; r < Rr; ++r) {
            #pragma unroll
            for (int i = 0; i < 2; ++i) {
                bf16x8 a = *(const bf16x8*)&S[cur][r][(n_off + i * 16 + fr) * 32 + fq];
                acc[r][i] = __builtin_amdgcn_mfma_f32_16x16x32_bf16(a, t, acc[r][i], 0, 0, 0);
            }
        }
    }

    const int en_ = n0 + n_off + ((l >> 4) << 2);
    const int em_ = m0 + m_off + (l & 15);
    #pragma unroll
    for (int i = 0; i < 2; ++i)
        #pragma unroll
        for (int rg = 0; rg < 4; ++rg) {
            const int n = en_ + i * 16 + rg;
            float* o = OUT + (((size_t)b * Nn + n) * Nn + em_) * Rr;
            #pragma unroll
            for (int r = 0; r < Rr; ++r)
                o[r] = acc[r][i][rg];
        }
}

extern "C" void kernel_launch(void* const* d_in, const int* in_sizes, int n_in,
                              void* d_out, int out_size, void* d_ws, size_t ws_size,
                              hipStream_t stream) {
    const float* features = (const float*)d_in[0]; // [16,256,768]
    const float* head_W   = (const float*)d_in[1]; // [2048,768]
    const float* head_b   = (const float*)d_in[2]; // [2048]
    const float* tail_W   = (const float*)d_in[3]; // [2048,768]
    const float* tail_b   = (const float*)d_in[4]; // [2048]
    const float* bil_W    = (const float*)d_in[5]; // [3,2048,2048]
    const float* bil_b    = (const float*)d_in[6]; // [3]
    float* out = (float*)d_out;                    // [16,256,256,3]

    // workspace layout (bf16), total ~52 MB
    char* ws = (char*)d_ws;
    bf16_t* Faug   = (bf16_t*)ws;  ws += (size_t)Mm * HA * 2;       // 7.3 MB
    bf16_t* tWaug  = (bf16_t*)ws;  ws += (size_t)HA * Pp * 2;       // 3.7 MB
    bf16_t* hWaug  = (bf16_t*)ws;  ws += (size_t)HA * KA * 2;       // 3.7 MB
    bf16_t* T1taug = (bf16_t*)ws;  ws += (size_t)Rr * HA * KA * 2;  // 11.2 MB
    bf16_t* Bop    = (bf16_t*)ws;  ws += (size_t)Rr * HA * HA * 2;  // 4.8 MB
    bf16_t* FG     = (bf16_t*)ws;  ws += (size_t)Mm * JA * 2;       // 22.0 MB

    // 1) build augmented operands (tiny/streaming; bil_W is consumed fp32-direct)
    build_Faug<<<Mm * (HA / 4) / 256, 256, 0, stream>>>(features, Faug);
    build_tWaug<<<dim3(Pp / 32, HA / 32), dim3(32, 8), 0, stream>>>(tail_W, tail_b, tWaug);
    build_hWaug<<<dim3(KA / 32, HA / 32), dim3(32, 8), 0, stream>>>(head_W, head_b, hWaug);

    // 2) T1taug[r] [896, 2048(+32)] = tWaug @ bil_W[r]^T — LDS-free wave GEMM
    t1_wave_kernel<<<dim3(Pp / 128, HA / 128, Rr), 256, 0, stream>>>(
        tWaug, bil_W, T1taug);
    fill_T1cols<<<(Rr * HA + 255) / 256, 256, 0, stream>>>(bil_b, T1taug);

    // 3) Bop[r] [896, 896] = T1taug[r] @ hWaug^T — LDS-free wave GEMM
    bop_wave_kernel<<<dim3(HA / 128, HA / 64, Rr), 256, 0, stream>>>(
        T1taug, hWaug, Bop);

    // 4) FG [4096, 2688] = Faug [4096,896] @ Bop^T [2688,896]
    gemm_nt_128<<<dim3(JA / 128, Mm / 128), 256, 0, stream>>>(
        Faug, HA,
        Bop, HA,
        FG, JA, HA);

    // 5) fused output GEMM over all r (K=896, biases already folded in)
    gemm_out_fused<<<dim3(Nn / 64, Nn / 64, Bb), 512, 0, stream>>>(FG, Faug, out);
}

// Round 9
// 270.995 us; speedup vs baseline: 1.4607x; 1.4607x over previous
//
#include <hip/hip_runtime.h>

// Problem constants
constexpr int Bb = 16;      // batch
constexpr int Nn = 256;     // regions
constexpr int Hh = 768;     // hidden
constexpr int Pp = 2048;    // proj dim
constexpr int Rr = 3;       // relation types
constexpr int Mm = Bb * Nn; // 4096 flattened rows
constexpr int HA = 896;     // augmented hidden (768 + 1 bias row + pad)
constexpr int KA = 2080;    // augmented K for Bop GEMM (2048 + 32)
constexpr int JA = Rr * HA; // 2688
constexpr int SK = 4;       // split-K factor for T1 / Bop

typedef __bf16 bf16_t;
typedef __bf16 bf16x8 __attribute__((ext_vector_type(8)));
typedef __bf16 bf16x4 __attribute__((ext_vector_type(4)));
typedef float  floatx4 __attribute__((ext_vector_type(4)));

// async global->LDS, 16B per lane; LDS dest = wave-uniform base + lane*16
__device__ __forceinline__ void gld_lds16(const void* g, void* l) {
    __builtin_amdgcn_global_load_lds(
        (__attribute__((address_space(1))) void*)g,
        (__attribute__((address_space(3))) void*)l,
        16, 0, 0);
}

// ---------------------------------------------------------------------------
// F_aug [4096, 896] bf16: cols 0..767 = F, col 768 = 1, cols 769..895 = 0
// ---------------------------------------------------------------------------
__global__ __launch_bounds__(256) void build_Faug(
    const float* __restrict__ F, bf16_t* __restrict__ out)
{
    const int idx = blockIdx.x * 256 + threadIdx.x;
    const int n = idx / (HA / 4), c4 = idx % (HA / 4);
    const int h = c4 * 4;
    bf16x4 o;
    if (h < Hh) {
        float4 v = *(const float4*)(F + (size_t)n * Hh + h);
        o = { (bf16_t)v.x, (bf16_t)v.y, (bf16_t)v.z, (bf16_t)v.w };
    } else {
        #pragma unroll
        for (int e = 0; e < 4; ++e) o[e] = (bf16_t)((h + e == Hh) ? 1.0f : 0.0f);
    }
    *(bf16x4*)(out + (size_t)n * HA + h) = o;
}

// ---------------------------------------------------------------------------
// tWaug [896, 2048]: rows j<768 = tW^T (tW[q,j]), row 768 = bt[q], rows>768 = 0
// ---------------------------------------------------------------------------
__global__ __launch_bounds__(256) void build_tWaug(
    const float* __restrict__ tW, const float* __restrict__ bt,
    bf16_t* __restrict__ out)
{
    __shared__ float t[32][33];
    const int j0 = blockIdx.y * 32, q0 = blockIdx.x * 32;
    const int tx = threadIdx.x, ty = threadIdx.y;
    #pragma unroll
    for (int s = 0; s < 4; ++s) {
        const int q = q0 + ty + s * 8, j = j0 + tx;
        t[ty + s * 8][tx] = (j < Hh) ? tW[(size_t)q * Hh + j] : 0.0f;
    }
    __syncthreads();
    #pragma unroll
    for (int s = 0; s < 4; ++s) {
        const int j = j0 + ty + s * 8, q = q0 + tx;
        float v = t[tx][ty + s * 8];
        if (j == Hh) v = bt[q];
        else if (j > Hh) v = 0.0f;
        out[(size_t)j * Pp + q] = (bf16_t)v;
    }
}

// ---------------------------------------------------------------------------
// hWaug [896, 2080]: rows h<768 = hW^T, row 768 = [bh | 1 @ p=2048], rows>768=0
// ---------------------------------------------------------------------------
__global__ __launch_bounds__(256) void build_hWaug(
    const float* __restrict__ hW, const float* __restrict__ bh,
    bf16_t* __restrict__ out)
{
    __shared__ float t[32][33];
    const int h0 = blockIdx.y * 32, p0 = blockIdx.x * 32;
    const int tx = threadIdx.x, ty = threadIdx.y;
    #pragma unroll
    for (int s = 0; s < 4; ++s) {
        const int p = p0 + ty + s * 8, h = h0 + tx;
        t[ty + s * 8][tx] = (p < Pp && h < Hh) ? hW[(size_t)p * Hh + h] : 0.0f;
    }
    __syncthreads();
    #pragma unroll
    for (int s = 0; s < 4; ++s) {
        const int h = h0 + ty + s * 8, p = p0 + tx;
        float v = t[tx][ty + s * 8];
        if (h == Hh) v = (p < Pp) ? bh[p] : (p == Pp ? 1.0f : 0.0f);
        else if (h > Hh) v = 0.0f;
        out[(size_t)h * KA + p] = (bf16_t)v;
    }
}

// ---------------------------------------------------------------------------
// T1 split-K GEMM: 128(M)x64(N) tile, A bf16 / B fp32 (in-kernel cvt), dbuf
// LDS, XOR-swizzled B staging. grid (Pp/64, HA/128, Rr*SK); z -> r=z/SK,s=z%SK.
// Each block does 16 K-steps (512 elems). Partials: P[s][r][HA][2048] bf16.
// ---------------------------------------------------------------------------
__global__ __launch_bounds__(256) void t1_split_kernel(
    const bf16_t* __restrict__ A,   // tWaug [HA, Pp]
    const float*  __restrict__ B,   // bil_W [Rr][Pp][Pp]
    bf16_t* __restrict__ P)         // partials [SK][Rr][HA][2048]
{
    const int r = blockIdx.z / SK;
    const int s = blockIdx.z % SK;
    const int kbase = s * (Pp / SK);           // elements
    B += (size_t)r * Pp * Pp;
    bf16_t* C = P + ((size_t)s * Rr + r) * HA * Pp;

    __shared__ bf16_t As[2][128 * 32];   // 8 KB per buf
    __shared__ float  Bs[2][64 * 32];    // 8 KB per buf

    const int tid = threadIdx.x;
    const int w = tid >> 6;
    const int l = tid & 63;
    const int m0 = blockIdx.y * 128;
    const int n0 = blockIdx.x * 64;

    const bf16_t* ga0 = A + (size_t)(m0 + (w << 4) + (l >> 2)) * Pp + ((l & 3) << 3) + kbase;
    const bf16_t* ga1 = ga0 + (size_t)64 * Pp;
    const int brow = (w << 3) + (l >> 3);
    const int bgrp = (l & 7) ^ (l >> 3);
    const float* gb0 = B + (size_t)(n0 + brow) * Pp + (bgrp << 2) + kbase;
    const float* gb1 = gb0 + (size_t)32 * Pp;

    const int wm = (w >> 1) << 6;
    const int wn = (w & 1) << 5;
    const int fr = l & 15;
    const int fq = (l >> 4) << 3;

    const int swz = fr & 7;
    const int cg0 = (l >> 4) << 1;
    const int off0 = ((cg0 ^ swz) << 2);
    const int off1 = (((cg0 + 1) ^ swz) << 2);

    floatx4 acc[4][2] = {};

    {
        gld_lds16(ga0, (char*)As[0] + (w << 10));
        gld_lds16(ga1, (char*)As[0] + 4096 + (w << 10));
        gld_lds16(gb0, (char*)Bs[0] + (w << 10));
        gld_lds16(gb1, (char*)Bs[0] + 4096 + (w << 10));
        ga0 += 32; ga1 += 32; gb0 += 32; gb1 += 32;
    }

    constexpr int steps = Pp / SK / 32;  // 16
    for (int k = 0; k < steps; ++k) {
        __syncthreads();
        const int cur = k & 1;
        if (k + 1 < steps) {
            gld_lds16(ga0, (char*)As[cur ^ 1] + (w << 10));
            gld_lds16(ga1, (char*)As[cur ^ 1] + 4096 + (w << 10));
            gld_lds16(gb0, (char*)Bs[cur ^ 1] + (w << 10));
            gld_lds16(gb1, (char*)Bs[cur ^ 1] + 4096 + (w << 10));
            ga0 += 32; ga1 += 32; gb0 += 32; gb1 += 32;
        }

        bf16x8 a[4], b[2];
        #pragma unroll
        for (int i = 0; i < 4; ++i)
            a[i] = *(const bf16x8*)&As[cur][(wm + i * 16 + fr) * 32 + fq];
        #pragma unroll
        for (int j = 0; j < 2; ++j) {
            const float* bp = &Bs[cur][(wn + j * 16 + fr) * 32];
            floatx4 x0 = *(const floatx4*)(bp + off0);
            floatx4 x1 = *(const floatx4*)(bp + off1);
            #pragma unroll
            for (int e = 0; e < 4; ++e) { b[j][e] = (bf16_t)x0[e]; b[j][e + 4] = (bf16_t)x1[e]; }
        }
        #pragma unroll
        for (int i = 0; i < 4; ++i)
            #pragma unroll
            for (int j = 0; j < 2; ++j)
                acc[i][j] = __builtin_amdgcn_mfma_f32_16x16x32_bf16(a[i], b[j], acc[i][j], 0, 0, 0);
    }

    const int em = m0 + wm + ((l >> 4) << 2);
    const int en = n0 + wn + (l & 15);
    #pragma unroll
    for (int i = 0; i < 4; ++i)
        #pragma unroll
        for (int j = 0; j < 2; ++j)
            #pragma unroll
            for (int rg = 0; rg < 4; ++rg)
                C[(size_t)(em + i * 16 + rg) * Pp + en + j * 16] = (bf16_t)acc[i][j][rg];
}

// ---------------------------------------------------------------------------
// T1 reduce: T1taug[r][j][c] = sum_s P[s][r][j][c] for c<2048; pad stripe
// c in [2048,2080): col 2048 = (j==768 ? bil_b[r] : 0), rest 0.
// one thread per 8 cols: Rr*HA*(KA/8) = 698880 threads.
// ---------------------------------------------------------------------------
__global__ __launch_bounds__(256) void t1_reduce_kernel(
    const bf16_t* __restrict__ P, const float* __restrict__ bil_b,
    bf16_t* __restrict__ T1)
{
    const int idx = blockIdx.x * 256 + threadIdx.x;
    if (idx >= Rr * HA * (KA / 8)) return;
    const int r = idx / (HA * (KA / 8));
    const int rem = idx % (HA * (KA / 8));
    const int j = rem / (KA / 8);
    const int c = (rem % (KA / 8)) * 8;
    bf16x8 o;
    if (c < Pp) {
        float acc[8] = {};
        #pragma unroll
        for (int s = 0; s < SK; ++s) {
            bf16x8 v = *(const bf16x8*)(P + (((size_t)s * Rr + r) * HA + j) * Pp + c);
            #pragma unroll
            for (int e = 0; e < 8; ++e) acc[e] += (float)v[e];
        }
        #pragma unroll
        for (int e = 0; e < 8; ++e) o[e] = (bf16_t)acc[e];
    } else {
        #pragma unroll
        for (int e = 0; e < 8; ++e) o[e] = (bf16_t)0.0f;
        if (c == Pp && j == Hh) o[0] = (bf16_t)bil_b[r];
    }
    *(bf16x8*)(T1 + ((size_t)r * HA + j) * KA + c) = o;
}

// ---------------------------------------------------------------------------
// Bop split-K GEMM: 64x64 tile bf16 NT, dbuf LDS. K=KA=2080 -> 65 steps,
// split {17,17,17,14}. grid (HA/64, HA/64, Rr*SK). Partials [SK][Rr][HA][HA].
// ---------------------------------------------------------------------------
__global__ __launch_bounds__(256) void bop_split_kernel(
    const bf16_t* __restrict__ A,   // T1taug [Rr][HA][KA]
    const bf16_t* __restrict__ Bm,  // hWaug [HA][KA]
    bf16_t* __restrict__ P)         // partials [SK][Rr][HA][HA]
{
    const int r = blockIdx.z / SK;
    const int s = blockIdx.z % SK;
    const int steps = (s < 3) ? 17 : 14;
    const int kbase = s * 17 * 32;
    A += (size_t)r * HA * KA;
    bf16_t* C = P + ((size_t)s * Rr + r) * HA * HA;

    __shared__ bf16_t As[2][64 * 32];
    __shared__ bf16_t Bs[2][64 * 32];

    const int tid = threadIdx.x;
    const int w = tid >> 6;
    const int l = tid & 63;
    const int m0 = blockIdx.y * 64;
    const int n0 = blockIdx.x * 64;

    const bf16_t* ga = A  + (size_t)(m0 + (tid >> 2)) * KA + ((tid & 3) << 3) + kbase;
    const bf16_t* gb = Bm + (size_t)(n0 + (tid >> 2)) * KA + ((tid & 3) << 3) + kbase;

    const int wm = (w >> 1) << 5;
    const int wn = (w & 1) << 5;
    const int fr = l & 15;
    const int fq = (l >> 4) << 3;

    floatx4 acc[2][2] = {};

    {
        gld_lds16(ga, (char*)As[0] + (w << 10));
        gld_lds16(gb, (char*)Bs[0] + (w << 10));
        ga += 32; gb += 32;
    }

    for (int k = 0; k < steps; ++k) {
        __syncthreads();
        const int cur = k & 1;
        if (k + 1 < steps) {
            gld_lds16(ga, (char*)As[cur ^ 1] + (w << 10));
            gld_lds16(gb, (char*)Bs[cur ^ 1] + (w << 10));
            ga += 32; gb += 32;
        }

        bf16x8 a[2], b[2];
        #pragma unroll
        for (int i = 0; i < 2; ++i) {
            a[i] = *(const bf16x8*)&As[cur][(wm + i * 16 + fr) * 32 + fq];
            b[i] = *(const bf16x8*)&Bs[cur][(wn + i * 16 + fr) * 32 + fq];
        }
        #pragma unroll
        for (int i = 0; i < 2; ++i)
            #pragma unroll
            for (int j = 0; j < 2; ++j)
                acc[i][j] = __builtin_amdgcn_mfma_f32_16x16x32_bf16(a[i], b[j], acc[i][j], 0, 0, 0);
    }

    const int em = m0 + wm + ((l >> 4) << 2);
    const int en = n0 + wn + (l & 15);
    #pragma unroll
    for (int i = 0; i < 2; ++i)
        #pragma unroll
        for (int j = 0; j < 2; ++j)
            #pragma unroll
            for (int rg = 0; rg < 4; ++rg)
                C[(size_t)(em + i * 16 + rg) * HA + en + j * 16] = (bf16_t)acc[i][j][rg];
}

// ---------------------------------------------------------------------------
// Bop reduce: Bop[r][j][c] = sum_s P[s][r][j][c]. Rr*HA*(HA/8) threads.
// ---------------------------------------------------------------------------
__global__ __launch_bounds__(256) void bop_reduce_kernel(
    const bf16_t* __restrict__ P, bf16_t* __restrict__ Bop)
{
    const int idx = blockIdx.x * 256 + threadIdx.x;
    if (idx >= Rr * HA * (HA / 8)) return;
    const int r = idx / (HA * (HA / 8));
    const int rem = idx % (HA * (HA / 8));
    const int j = rem / (HA / 8);
    const int c = (rem % (HA / 8)) * 8;
    float acc[8] = {};
    #pragma unroll
    for (int s = 0; s < SK; ++s) {
        bf16x8 v = *(const bf16x8*)(P + (((size_t)s * Rr + r) * HA + j) * HA + c);
        #pragma unroll
        for (int e = 0; e < 8; ++e) acc[e] += (float)v[e];
    }
    bf16x8 o;
    #pragma unroll
    for (int e = 0; e < 8; ++e) o[e] = (bf16_t)acc[e];
    *(bf16x8*)(Bop + ((size_t)r * HA + j) * HA + c) = o;
}

// ---------------------------------------------------------------------------
// 128x128-tile bf16 NT GEMM, double-buffered LDS (for FG)
// ---------------------------------------------------------------------------
__global__ __launch_bounds__(256) void gemm_nt_128(
    const bf16_t* __restrict__ A, int lda,
    const bf16_t* __restrict__ B, int ldb,
    bf16_t* __restrict__ C, int ldc, int K)
{
    __shared__ bf16_t As[2][128 * 32];
    __shared__ bf16_t Bs[2][128 * 32];

    const int tid = threadIdx.x;
    const int w = tid >> 6;
    const int l = tid & 63;
    const int m0 = blockIdx.y * 128;
    const int n0 = blockIdx.x * 128;

    const int srow = (w << 4) + (l >> 2);
    const int scol = (l & 3) << 3;
    const bf16_t* ga0 = A + (size_t)(m0 + srow) * lda + scol;
    const bf16_t* ga1 = ga0 + (size_t)64 * lda;
    const bf16_t* gb0 = B + (size_t)(n0 + srow) * ldb + scol;
    const bf16_t* gb1 = gb0 + (size_t)64 * ldb;

    const int wm = (w >> 1) << 6;
    const int wn = (w & 1) << 6;
    const int fr = l & 15;
    const int fq = (l >> 4) << 3;

    floatx4 acc[4][4] = {};

    {
        char* a = (char*)As[0] + (w << 10);
        char* b = (char*)Bs[0] + (w << 10);
        gld_lds16(ga0, a); gld_lds16(ga1, a + 4096);
        gld_lds16(gb0, b); gld_lds16(gb1, b + 4096);
        ga0 += 32; ga1 += 32; gb0 += 32; gb1 += 32;
    }

    const int steps = K >> 5;
    for (int k = 0; k < steps; ++k) {
        __syncthreads();
        const int cur = k & 1;
        if (k + 1 < steps) {
            char* a = (char*)As[cur ^ 1] + (w << 10);
            char* b = (char*)Bs[cur ^ 1] + (w << 10);
            gld_lds16(ga0, a); gld_lds16(ga1, a + 4096);
            gld_lds16(gb0, b); gld_lds16(gb1, b + 4096);
            ga0 += 32; ga1 += 32; gb0 += 32; gb1 += 32;
        }

        bf16x8 a[4], b[4];
        #pragma unroll
        for (int i = 0; i < 4; ++i) {
            a[i] = *(const bf16x8*)&As[cur][(wm + i * 16 + fr) * 32 + fq];
            b[i] = *(const bf16x8*)&Bs[cur][(wn + i * 16 + fr) * 32 + fq];
        }
        #pragma unroll
        for (int i = 0; i < 4; ++i)
            #pragma unroll
            for (int j = 0; j < 4; ++j)
                acc[i][j] = __builtin_amdgcn_mfma_f32_16x16x32_bf16(a[i], b[j], acc[i][j], 0, 0, 0);
    }

    const int em = m0 + wm + ((l >> 4) << 2);
    const int en = n0 + wn + (l & 15);
    #pragma unroll
    for (int j = 0; j < 4; ++j) {
        const int n = en + j * 16;
        #pragma unroll
        for (int i = 0; i < 4; ++i) {
            #pragma unroll
            for (int rg = 0; rg < 4; ++rg)
                C[(size_t)(em + i * 16 + rg) * ldc + n] = (bf16_t)(acc[i][j][rg]);
        }
    }
}

// ---------------------------------------------------------------------------
// fused output GEMM, all 3 r per block, dbuf LDS, K=896, 512 threads
//   logits[b,n,m,r] = sum_h FG[b*Nn+n, r*HA+h] * Faug[b*Nn+m, h]
// grid (Nn/64, Nn/64, Bb) = 256 blocks.
// ---------------------------------------------------------------------------
__global__ __launch_bounds__(512) void gemm_out_fused(
    const bf16_t* __restrict__ FG,    // [Mm, JA]
    const bf16_t* __restrict__ FA,    // [Mm, HA]
    float* __restrict__ OUT)
{
    __shared__ bf16_t S[2][4][64 * 32];  // tiles 0..2 = FG r, 3 = Faug (32KB)

    const int b = blockIdx.z;
    const int n0 = blockIdx.y * 64;
    const int m0 = blockIdx.x * 64;

    const int tid = threadIdx.x;
    const int w = tid >> 6;      // 0..7
    const int l = tid & 63;

    const int srow = ((w & 3) << 4) + (l >> 2);
    const int scol = (l & 3) << 3;
    const int t0 = w >> 2;
    const bf16_t* g0 = FG + (size_t)(b * Nn + n0 + srow) * JA + t0 * HA + scol;
    const bf16_t* g1 = (t0 == 0)
        ? FG + (size_t)(b * Nn + n0 + srow) * JA + 2 * HA + scol
        : FA + (size_t)(b * Nn + m0 + srow) * HA + scol;

    const int n_off = (w >> 2) << 5;
    const int m_off = (w & 3) << 4;
    const int fr = l & 15;
    const int fq = (l >> 4) << 3;

    floatx4 acc[Rr][2] = {};

    {
        char* base = (char*)&S[0][0][0];
        gld_lds16(g0, base + (w << 10));        g0 += 32;
        gld_lds16(g1, base + 8192 + (w << 10)); g1 += 32;
    }

    constexpr int STEPS = HA / 32; // 28
    for (int k = 0; k < STEPS; ++k) {
        __syncthreads();
        const int cur = k & 1;
        if (k + 1 < STEPS) {
            char* base = (char*)&S[cur ^ 1][0][0];
            gld_lds16(g0, base + (w << 10));        g0 += 32;
            gld_lds16(g1, base + 8192 + (w << 10)); g1 += 32;
        }

        bf16x8 t = *(const bf16x8*)&S[cur][3][(m_off + fr) * 32 + fq];
        #pragma unroll
        for (int r = 0; r < Rr; ++r) {
            #pragma unroll
            for (int i = 0; i < 2; ++i) {
                bf16x8 a = *(const bf16x8*)&S[cur][r][(n_off + i * 16 + fr) * 32 + fq];
                acc[r][i] = __builtin_amdgcn_mfma_f32_16x16x32_bf16(a, t, acc[r][i], 0, 0, 0);
            }
        }
    }

    const int en_ = n0 + n_off + ((l >> 4) << 2);
    const int em_ = m0 + m_off + (l & 15);
    #pragma unroll
    for (int i = 0; i < 2; ++i)
        #pragma unroll
        for (int rg = 0; rg < 4; ++rg) {
            const int n = en_ + i * 16 + rg;
            float* o = OUT + (((size_t)b * Nn + n) * Nn + em_) * Rr;
            #pragma unroll
            for (int r = 0; r < Rr; ++r)
                o[r] = acc[r][i][rg];
        }
}

extern "C" void kernel_launch(void* const* d_in, const int* in_sizes, int n_in,
                              void* d_out, int out_size, void* d_ws, size_t ws_size,
                              hipStream_t stream) {
    const float* features = (const float*)d_in[0]; // [16,256,768]
    const float* head_W   = (const float*)d_in[1]; // [2048,768]
    const float* head_b   = (const float*)d_in[2]; // [2048]
    const float* tail_W   = (const float*)d_in[3]; // [2048,768]
    const float* tail_b   = (const float*)d_in[4]; // [2048]
    const float* bil_W    = (const float*)d_in[5]; // [3,2048,2048]
    const float* bil_b    = (const float*)d_in[6]; // [3]
    float* out = (float*)d_out;                    // [16,256,256,3]

    // workspace layout (bf16), total ~94 MB
    char* ws = (char*)d_ws;
    bf16_t* Faug   = (bf16_t*)ws;  ws += (size_t)Mm * HA * 2;            // 7.3 MB
    bf16_t* tWaug  = (bf16_t*)ws;  ws += (size_t)HA * Pp * 2;            // 3.7 MB
    bf16_t* hWaug  = (bf16_t*)ws;  ws += (size_t)HA * KA * 2;            // 3.7 MB
    bf16_t* T1taug = (bf16_t*)ws;  ws += (size_t)Rr * HA * KA * 2;       // 11.2 MB
    bf16_t* Bop    = (bf16_t*)ws;  ws += (size_t)Rr * HA * HA * 2;       // 4.8 MB
    bf16_t* FG     = (bf16_t*)ws;  ws += (size_t)Mm * JA * 2;            // 22.0 MB
    bf16_t* T1part = (bf16_t*)ws;  ws += (size_t)SK * Rr * HA * Pp * 2;  // 22.0 MB
    bf16_t* Bopart = (bf16_t*)ws;  ws += (size_t)SK * Rr * HA * HA * 2;  // 19.3 MB

    // 1) build augmented operands
    build_Faug<<<Mm * (HA / 4) / 256, 256, 0, stream>>>(features, Faug);
    build_tWaug<<<dim3(Pp / 32, HA / 32), dim3(32, 8), 0, stream>>>(tail_W, tail_b, tWaug);
    build_hWaug<<<dim3(KA / 32, HA / 32), dim3(32, 8), 0, stream>>>(head_W, head_b, hWaug);

    // 2) T1 = tWaug @ bil_W[r]^T, split-K x4 + reduce (reduce writes pad cols)
    t1_split_kernel<<<dim3(Pp / 64, HA / 128, Rr * SK), 256, 0, stream>>>(
        tWaug, bil_W, T1part);
    t1_reduce_kernel<<<(Rr * HA * (KA / 8) + 255) / 256, 256, 0, stream>>>(
        T1part, bil_b, T1taug);

    // 3) Bop[r] = T1taug[r] @ hWaug^T, split-K x4 + reduce
    bop_split_kernel<<<dim3(HA / 64, HA / 64, Rr * SK), 256, 0, stream>>>(
        T1taug, hWaug, Bopart);
    bop_reduce_kernel<<<(Rr * HA * (HA / 8) + 255) / 256, 256, 0, stream>>>(
        Bopart, Bop);

    // 4) FG [4096, 2688] = Faug [4096,896] @ Bop^T [2688,896]
    gemm_nt_128<<<dim3(JA / 128, Mm / 128), 256, 0, stream>>>(
        Faug, HA,
        Bop, HA,
        FG, JA, HA);

    // 5) fused output GEMM over all r (K=896, biases already folded in)
    gemm_out_fused<<<dim3(Nn / 64, Nn / 64, Bb), 512, 0, stream>>>(FG, Faug, out);
}